// Round 4
// baseline (558.371 us; speedup 1.0000x reference)
//
#include <hip/hip_runtime.h>
#include <hip/hip_bf16.h>
#include <cstdint>
#include <cstddef>

#define T_LEN 2048
#define BATCH 32
#define DIM 512
#define M_TOT (T_LEN * BATCH)   // 65536
#define K_DIM DIM               // 512
#define N1 (2 * DIM)            // 1024
#define NCHUNK 64
#define CLEN (T_LEN / NCHUNK)   // 32
#define BD (BATCH * DIM)        // 16384
#define MT_TILES (M_TOT / 128)  // 512

typedef unsigned short ushort_t;
typedef __attribute__((ext_vector_type(8))) short short8;
typedef __attribute__((ext_vector_type(4))) float floatx4;
typedef __attribute__((ext_vector_type(4))) unsigned short ushort4v;

__device__ __forceinline__ float bf2f(ushort_t u) {
  union { unsigned int i; float f; } v;
  v.i = ((unsigned int)u) << 16;
  return v.f;
}
__device__ __forceinline__ ushort_t f2bf(float f) {
  union { float f; unsigned int i; } v;
  v.f = f;
  unsigned int x = v.i;
  return (ushort_t)((x + 0x7fffu + ((x >> 16) & 1u)) >> 16);
}

__device__ __forceinline__ void async16(const void* gp, void* lp) {
  __builtin_amdgcn_global_load_lds(
      (__attribute__((address_space(1))) void*)(void*)gp,
      (__attribute__((address_space(3))) void*)lp, 16, 0, 0);
}

// ---------------- convert fp32 -> bf16 (vector x4) ----------------
__global__ __launch_bounds__(256) void cvt_f32_bf16(const float* __restrict__ in,
                                                    ushort_t* __restrict__ out,
                                                    int n4) {
  int i = blockIdx.x * 256 + threadIdx.x;
  if (i >= n4) return;
  const floatx4 v = *((const floatx4*)in + i);
  ushort4v o;
  o.x = f2bf(v.x); o.y = f2bf(v.y); o.z = f2bf(v.z); o.w = f2bf(v.w);
  *((ushort4v*)out + i) = o;
}

// ---------------- in_proj bf16 MFMA GEMM (round-0 proven version) ----------
// C = A[M,K] * B[N,K]^T, 128x128 tile, BK=64, 256 threads (4 waves, 2x2).
// ~3 blocks/CU: inter-block TLP hides staging latency + epilogue drain at
// this short-K shape (1-block/CU pipelined variants measured SLOWER).
// Epilogue fuses bias + sigmoid gate (z half -> B*z, g half -> A*sigmoid).
__global__ __launch_bounds__(256, 2) void gemm_in(
    const ushort_t* __restrict__ Ag, const ushort_t* __restrict__ Bg,
    const float* __restrict__ bias, const float* __restrict__ Avec,
    const float* __restrict__ Bvec, ushort_t* __restrict__ out0,
    ushort_t* __restrict__ out1) {
  __shared__ __align__(16) ushort_t As[128 * 64];
  __shared__ __align__(16) ushort_t Bs[128 * 64];
  const int tid = threadIdx.x;
  const int lane = tid & 63;
  const int wid = tid >> 6;
  const int wave_m = wid >> 1;
  const int wave_n = wid & 1;

  const int bid = blockIdx.x;
  const int xcd = bid & 7;
  const int slot = bid >> 3;
  const int mt = xcd * (MT_TILES / 8) + slot / 8;
  const int nt = slot % 8;
  const int m0 = mt * 128;
  const int n0 = nt * 128;

  floatx4 acc[4][4] = {};

  const int sr = tid >> 3;  // 0..31: row within a 32-row staging group
  const int sc = tid & 7;   // 16B chunk slot within the row

  for (int k0 = 0; k0 < K_DIM; k0 += 64) {
    __syncthreads();
#pragma unroll
    for (int i = 0; i < 4; i++) {
      const int r = i * 32 + sr;
      const int cg = sc ^ (r & 7);  // swizzled source chunk
      async16(Ag + (size_t)(m0 + r) * K_DIM + k0 + cg * 8,
              (char*)As + (i * 32 + wid * 8) * 128);
      async16(Bg + (size_t)(n0 + r) * K_DIM + k0 + cg * 8,
              (char*)Bs + (i * 32 + wid * 8) * 128);
    }
    __syncthreads();
#pragma unroll
    for (int kk = 0; kk < 2; kk++) {
      const int jc = kk * 4 + (lane >> 4);
      short8 af[4], bfr[4];
#pragma unroll
      for (int im = 0; im < 4; im++) {
        const int row = wave_m * 64 + im * 16 + (lane & 15);
        af[im] = *(const short8*)((const char*)As + row * 128 +
                                  ((jc ^ (row & 7)) * 16));
      }
#pragma unroll
      for (int in = 0; in < 4; in++) {
        const int row = wave_n * 64 + in * 16 + (lane & 15);
        bfr[in] = *(const short8*)((const char*)Bs + row * 128 +
                                   ((jc ^ (row & 7)) * 16));
      }
#pragma unroll
      for (int im = 0; im < 4; im++)
#pragma unroll
        for (int in = 0; in < 4; in++)
          acc[im][in] = __builtin_amdgcn_mfma_f32_16x16x32_bf16(
              af[im], bfr[in], acc[im][in], 0, 0, 0);
    }
  }

#pragma unroll
  for (int im = 0; im < 4; im++) {
#pragma unroll
    for (int in = 0; in < 4; in++) {
      const int col = n0 + wave_n * 64 + in * 16 + (lane & 15);
#pragma unroll
      for (int r = 0; r < 4; r++) {
        const int row = m0 + wave_m * 64 + im * 16 + (lane >> 4) * 4 + r;
        float val = acc[im][in][r] + bias[col];
        if (col < DIM) {
          out0[(size_t)row * DIM + col] = f2bf(Bvec[col] * val);
        } else {
          const int d = col - DIM;
          const float s = 1.f / (1.f + __expf(-val));
          out1[(size_t)row * DIM + d] = f2bf(Avec[d] * s);
        }
      }
    }
  }
}

// ---------------- fused out_proj + residual + layernorm ----------------
// Tile 64 rows x 512 cols (FULL N) so each block owns complete output rows:
// LN runs in the epilogue on f32 accumulators. Eliminates the 64 MB out_ws
// write + 64 MB re-read + the separate ln kernel (and improves precision:
// no bf16 rounding between out_proj and LN).
// 512 threads = 8 waves, each wave 64x64 cols (wid = wave_n). acc[4][4]
// (64 AGPR) + ~64 VGPR -> 4 waves/SIMD -> 2 blocks/CU (LDS 76.5 KB).
__global__ __launch_bounds__(512, 4) void gemm_ln(
    const ushort_t* __restrict__ Ag,   // h bf16 [M_TOT][DIM]
    const ushort_t* __restrict__ Bg,   // W_out bf16 [DIM][DIM]
    const float* __restrict__ bias,    // b_out
    const float* __restrict__ x,       // residual f32 [M_TOT][DIM]
    const float* __restrict__ gamma, const float* __restrict__ beta,
    float* __restrict__ out) {
  __shared__ __align__(16) ushort_t As[64 * 64];    // 8 KB
  __shared__ __align__(16) ushort_t Bs[512 * 64];   // 64 KB
  __shared__ float red[64][8][2];                   // 4 KB
  __shared__ float stat[64][2];                     // 0.5 KB
  const int tid = threadIdx.x;
  const int lane = tid & 63;
  const int wid = tid >> 6;     // wave_n 0..7 -> 64-col slice
  const int m0 = blockIdx.x * 64;

  floatx4 acc[4][4] = {};
  const int sr = tid >> 3;      // 0..63
  const int sc = tid & 7;

  for (int k0 = 0; k0 < K_DIM; k0 += 64) {
    __syncthreads();
    {  // A: 64 rows x 8 chunks = 512 chunks, 1 load/thread
      const int cg = sc ^ (sr & 7);
      async16(Ag + (size_t)(m0 + sr) * K_DIM + k0 + cg * 8,
              (char*)As + tid * 16);
    }
#pragma unroll
    for (int i = 0; i < 8; i++) {  // B: 512 rows, 8 loads/thread
      const int r = i * 64 + sr;
      const int cg = sc ^ (r & 7);
      async16(Bg + (size_t)r * K_DIM + k0 + cg * 8,
              (char*)Bs + i * 8192 + tid * 16);
    }
    __syncthreads();  // implies vmcnt(0): staged tile landed
#pragma unroll
    for (int kk = 0; kk < 2; kk++) {
      const int jc = kk * 4 + (lane >> 4);
      short8 af[4], bfr[4];
#pragma unroll
      for (int im = 0; im < 4; im++) {
        const int row = im * 16 + (lane & 15);
        af[im] = *(const short8*)((const char*)As + row * 128 +
                                  ((jc ^ (row & 7)) * 16));
      }
#pragma unroll
      for (int in = 0; in < 4; in++) {
        const int row = wid * 64 + in * 16 + (lane & 15);
        bfr[in] = *(const short8*)((const char*)Bs + row * 128 +
                                   ((jc ^ (row & 7)) * 16));
      }
#pragma unroll
      for (int im = 0; im < 4; im++)
#pragma unroll
        for (int in = 0; in < 4; in++)
          acc[im][in] = __builtin_amdgcn_mfma_f32_16x16x32_bf16(
              af[im], bfr[in], acc[im][in], 0, 0, 0);
    }
  }

  // ---- epilogue: y = x + (acc + b_out); LN over rows of 512 ----
  // thread frags: rows im*16+(lane>>4)*4+r (16), cols wid*64+in*16+(lane&15) (4)
  float bcol[4];
#pragma unroll
  for (int in = 0; in < 4; in++)
    bcol[in] = bias[wid * 64 + in * 16 + (lane & 15)];

  // phase 1: per-row partial (sum, sumsq) over this wave's 64-col slice
#pragma unroll
  for (int im = 0; im < 4; im++) {
#pragma unroll
    for (int r = 0; r < 4; r++) {
      const int rowl = im * 16 + (lane >> 4) * 4 + r;
      const size_t rowg = (size_t)(m0 + rowl);
      float s = 0.f, ss = 0.f;
#pragma unroll
      for (int in = 0; in < 4; in++) {
        const int col = wid * 64 + in * 16 + (lane & 15);
        const float y = x[rowg * DIM + col] + acc[im][in][r] + bcol[in];
        s += y; ss += y * y;
      }
#pragma unroll
      for (int m = 8; m >= 1; m >>= 1) {  // reduce the 16-lane col group
        s += __shfl_xor(s, m, 64);
        ss += __shfl_xor(ss, m, 64);
      }
      if ((lane & 15) == 0) {
        red[rowl][wid][0] = s;
        red[rowl][wid][1] = ss;
      }
    }
  }
  __syncthreads();
  if (tid < 64) {
    float s = 0.f, ss = 0.f;
#pragma unroll
    for (int w = 0; w < 8; w++) { s += red[tid][w][0]; ss += red[tid][w][1]; }
    const float mean = s * (1.f / DIM);
    const float var = ss * (1.f / DIM) - mean * mean;
    stat[tid][0] = mean;
    stat[tid][1] = rsqrtf(var + 1e-5f);
  }
  __syncthreads();
  // phase 2: recompute y (acc still live in AGPRs; x is L2-warm), normalize
#pragma unroll
  for (int im = 0; im < 4; im++) {
#pragma unroll
    for (int r = 0; r < 4; r++) {
      const int rowl = im * 16 + (lane >> 4) * 4 + r;
      const size_t rowg = (size_t)(m0 + rowl);
      const float mean = stat[rowl][0], rstd = stat[rowl][1];
#pragma unroll
      for (int in = 0; in < 4; in++) {
        const int col = wid * 64 + in * 16 + (lane & 15);
        const float y = x[rowg * DIM + col] + acc[im][in][r] + bcol[in];
        out[rowg * DIM + col] = (y - mean) * rstd * gamma[col] + beta[col];
      }
    }
  }
}

// ---------------- chunked scan ----------------
// h_t = a_t * h_{t-1} + bz_t, independent per (b,d) pair, t in [0,2048).

// Pass 1: per chunk, local scan from h=0; emit prod(a) and local h_end.
// 8 cols/thread, 16 B loads.
__global__ __launch_bounds__(256) void scan_pass1(
    const ushort_t* __restrict__ a_arr, const ushort_t* __restrict__ bz_arr,
    float* __restrict__ pout, float* __restrict__ hout) {
  const int tid = blockIdx.x * 256 + threadIdx.x;  // 64*2048 threads
  const int c = tid >> 11;
  const int q = tid & 2047;
  size_t base = (size_t)(c * CLEN) * BD + q * 8;
  float h[8], p[8];
#pragma unroll
  for (int j = 0; j < 8; j++) { h[j] = 0.f; p[j] = 1.f; }
#pragma unroll 4
  for (int t = 0; t < CLEN; t++) {
    short8 av = *(const short8*)(a_arr + base + (size_t)t * BD);
    short8 bv = *(const short8*)(bz_arr + base + (size_t)t * BD);
#pragma unroll
    for (int j = 0; j < 8; j++) {
      const float a = bf2f((ushort_t)av[j]);
      h[j] = a * h[j] + bf2f((ushort_t)bv[j]);
      p[j] *= a;
    }
  }
  const size_t ci = (size_t)c * BD + q * 8;
  *(floatx4*)(pout + ci) = (floatx4){p[0], p[1], p[2], p[3]};
  *(floatx4*)(pout + ci + 4) = (floatx4){p[4], p[5], p[6], p[7]};
  *(floatx4*)(hout + ci) = (floatx4){h[0], h[1], h[2], h[3]};
  *(floatx4*)(hout + ci + 4) = (floatx4){h[4], h[5], h[6], h[7]};
}

// Pass 2: sequentially combine chunk carries; 1 col/thread (16384 threads)
// for occupancy — the old 4096-thread version was latency-starved.
__global__ __launch_bounds__(256) void scan_pass2(
    const float* __restrict__ p, const float* __restrict__ hend,
    float* __restrict__ carry) {
  const int q = blockIdx.x * 256 + threadIdx.x;  // 0..16383
  float h = 0.f;
#pragma unroll 4
  for (int c = 0; c < NCHUNK; c++) {
    const size_t ci = (size_t)c * BD + q;
    const float pv = p[ci];
    const float hv = hend[ci];
    carry[ci] = h;
    h = hv + pv * h;
  }
}

// Pass 3: re-scan each chunk with its carry-in, write h (bf16). 8 cols/thread.
__global__ __launch_bounds__(256) void scan_pass3(
    const ushort_t* __restrict__ a_arr, const ushort_t* __restrict__ bz_arr,
    const float* __restrict__ carry, ushort_t* __restrict__ h_arr) {
  const int tid = blockIdx.x * 256 + threadIdx.x;
  const int c = tid >> 11;
  const int q = tid & 2047;
  size_t base = (size_t)(c * CLEN) * BD + q * 8;
  const size_t ci = (size_t)c * BD + q * 8;
  floatx4 c0 = *(const floatx4*)(carry + ci);
  floatx4 c1 = *(const floatx4*)(carry + ci + 4);
  float h[8] = {c0.x, c0.y, c0.z, c0.w, c1.x, c1.y, c1.z, c1.w};
#pragma unroll 4
  for (int t = 0; t < CLEN; t++) {
    short8 av = *(const short8*)(a_arr + base + (size_t)t * BD);
    short8 bv = *(const short8*)(bz_arr + base + (size_t)t * BD);
    short8 o;
#pragma unroll
    for (int j = 0; j < 8; j++) {
      h[j] = bf2f((ushort_t)av[j]) * h[j] + bf2f((ushort_t)bv[j]);
      o[j] = (short)f2bf(h[j]);
    }
    *(short8*)(h_arr + base + (size_t)t * BD) = o;
  }
}

// ---------------- launch ----------------
extern "C" void kernel_launch(void* const* d_in, const int* in_sizes, int n_in,
                              void* d_out, int out_size, void* d_ws,
                              size_t ws_size, hipStream_t stream) {
  const float* x = (const float*)d_in[0];
  const float* W_in = (const float*)d_in[1];
  const float* b_in = (const float*)d_in[2];
  const float* W_out = (const float*)d_in[3];
  const float* b_out = (const float*)d_in[4];
  const float* Avec = (const float*)d_in[5];
  const float* Bvec = (const float*)d_in[6];
  const float* gamma = (const float*)d_in[7];
  const float* beta = (const float*)d_in[8];
  float* out = (float*)d_out;

  char* ws = (char*)d_ws;
  const size_t SZ64 = (size_t)M_TOT * DIM * 2;  // 64 MiB
  ushort_t* xb = (ushort_t*)ws;                  // x bf16; later reused as h
  ushort_t* gA = (ushort_t*)(ws + SZ64);         // gate*A
  ushort_t* bz = (ushort_t*)(ws + 2 * SZ64);     // B*z
  ushort_t* wib = (ushort_t*)(ws + 3 * SZ64);
  ushort_t* wob = (ushort_t*)(ws + 3 * SZ64 + (size_t)N1 * K_DIM * 2);
  char* p0 = ws + 3 * SZ64 + (size_t)N1 * K_DIM * 2 + (size_t)DIM * K_DIM * 2;
  float* pc = (float*)p0;                                   // 4 MiB
  float* hc = (float*)(p0 + (size_t)NCHUNK * BD * 4);       // 4 MiB
  float* cc = (float*)(p0 + 2 * (size_t)NCHUNK * BD * 4);   // 4 MiB

  // converts
  cvt_f32_bf16<<<(M_TOT * DIM / 4 + 255) / 256, 256, 0, stream>>>(
      x, xb, M_TOT * DIM / 4);
  cvt_f32_bf16<<<(N1 * K_DIM / 4 + 255) / 256, 256, 0, stream>>>(
      W_in, wib, N1 * K_DIM / 4);
  cvt_f32_bf16<<<(DIM * K_DIM / 4 + 255) / 256, 256, 0, stream>>>(
      W_out, wob, DIM * K_DIM / 4);

  // in_proj + gate epilogue (128x128 tiles, 512 m-tiles x 8 n-tiles)
  gemm_in<<<MT_TILES * 8, 256, 0, stream>>>(
      xb, wib, b_in, Avec, Bvec, bz, gA);

  // chunked scan (8 cols/thread in passes 1,3; 1 col/thread in pass 2)
  scan_pass1<<<NCHUNK * (BD / 8) / 256, 256, 0, stream>>>(gA, bz, pc, hc);
  scan_pass2<<<BD / 256, 256, 0, stream>>>(pc, hc, cc);
  scan_pass3<<<NCHUNK * (BD / 8) / 256, 256, 0, stream>>>(gA, bz, cc, xb);

  // fused out_proj + residual + layernorm (h = xb region)
  gemm_ln<<<M_TOT / 64, 512, 0, stream>>>(
      xb, wob, b_out, x, gamma, beta, out);
}

// Round 5
// 508.597 us; speedup vs baseline: 1.0979x; 1.0979x over previous
//
#include <hip/hip_runtime.h>
#include <hip/hip_bf16.h>
#include <cstdint>
#include <cstddef>

#define T_LEN 2048
#define BATCH 32
#define DIM 512
#define M_TOT (T_LEN * BATCH)   // 65536
#define K_DIM DIM               // 512
#define N1 (2 * DIM)            // 1024
#define NCHUNK 64
#define CLEN (T_LEN / NCHUNK)   // 32
#define BD (BATCH * DIM)        // 16384
#define MT_TILES (M_TOT / 128)  // 512

typedef unsigned short ushort_t;
typedef __attribute__((ext_vector_type(8))) short short8;
typedef __attribute__((ext_vector_type(4))) float floatx4;
typedef __attribute__((ext_vector_type(4))) unsigned short ushort4v;

__device__ __forceinline__ float bf2f(ushort_t u) {
  union { unsigned int i; float f; } v;
  v.i = ((unsigned int)u) << 16;
  return v.f;
}
__device__ __forceinline__ ushort_t f2bf(float f) {
  union { float f; unsigned int i; } v;
  v.f = f;
  unsigned int x = v.i;
  return (ushort_t)((x + 0x7fffu + ((x >> 16) & 1u)) >> 16);
}

__device__ __forceinline__ void async16(const void* gp, void* lp) {
  __builtin_amdgcn_global_load_lds(
      (__attribute__((address_space(1))) void*)(void*)gp,
      (__attribute__((address_space(3))) void*)lp, 16, 0, 0);
}

// ---------------- convert fp32 -> bf16 (vector x4) ----------------
__global__ __launch_bounds__(256) void cvt_f32_bf16(const float* __restrict__ in,
                                                    ushort_t* __restrict__ out,
                                                    int n4) {
  int i = blockIdx.x * 256 + threadIdx.x;
  if (i >= n4) return;
  const floatx4 v = *((const floatx4*)in + i);
  ushort4v o;
  o.x = f2bf(v.x); o.y = f2bf(v.y); o.z = f2bf(v.z); o.w = f2bf(v.w);
  *((ushort4v*)out + i) = o;
}

// ---------------- in_proj bf16 MFMA GEMM (round-0 proven version) ----------
// C = A[M,K] * B[N,K]^T, 128x128 tile, BK=64, 256 threads (4 waves, 2x2).
// ~3 blocks/CU: inter-block TLP hides staging latency + epilogue drain at
// this short-K shape (1-block/CU pipelined variants measured SLOWER).
// Epilogue fuses bias + sigmoid gate (z half -> B*z, g half -> A*sigmoid).
__global__ __launch_bounds__(256, 2) void gemm_in(
    const ushort_t* __restrict__ Ag, const ushort_t* __restrict__ Bg,
    const float* __restrict__ bias, const float* __restrict__ Avec,
    const float* __restrict__ Bvec, ushort_t* __restrict__ out0,
    ushort_t* __restrict__ out1) {
  __shared__ __align__(16) ushort_t As[128 * 64];
  __shared__ __align__(16) ushort_t Bs[128 * 64];
  const int tid = threadIdx.x;
  const int lane = tid & 63;
  const int wid = tid >> 6;
  const int wave_m = wid >> 1;
  const int wave_n = wid & 1;

  const int bid = blockIdx.x;
  const int xcd = bid & 7;
  const int slot = bid >> 3;
  const int mt = xcd * (MT_TILES / 8) + slot / 8;
  const int nt = slot % 8;
  const int m0 = mt * 128;
  const int n0 = nt * 128;

  floatx4 acc[4][4] = {};

  const int sr = tid >> 3;  // 0..31: row within a 32-row staging group
  const int sc = tid & 7;   // 16B chunk slot within the row

  for (int k0 = 0; k0 < K_DIM; k0 += 64) {
    __syncthreads();
#pragma unroll
    for (int i = 0; i < 4; i++) {
      const int r = i * 32 + sr;
      const int cg = sc ^ (r & 7);  // swizzled source chunk
      async16(Ag + (size_t)(m0 + r) * K_DIM + k0 + cg * 8,
              (char*)As + (i * 32 + wid * 8) * 128);
      async16(Bg + (size_t)(n0 + r) * K_DIM + k0 + cg * 8,
              (char*)Bs + (i * 32 + wid * 8) * 128);
    }
    __syncthreads();
#pragma unroll
    for (int kk = 0; kk < 2; kk++) {
      const int jc = kk * 4 + (lane >> 4);
      short8 af[4], bfr[4];
#pragma unroll
      for (int im = 0; im < 4; im++) {
        const int row = wave_m * 64 + im * 16 + (lane & 15);
        af[im] = *(const short8*)((const char*)As + row * 128 +
                                  ((jc ^ (row & 7)) * 16));
      }
#pragma unroll
      for (int in = 0; in < 4; in++) {
        const int row = wave_n * 64 + in * 16 + (lane & 15);
        bfr[in] = *(const short8*)((const char*)Bs + row * 128 +
                                   ((jc ^ (row & 7)) * 16));
      }
#pragma unroll
      for (int im = 0; im < 4; im++)
#pragma unroll
        for (int in = 0; in < 4; in++)
          acc[im][in] = __builtin_amdgcn_mfma_f32_16x16x32_bf16(
              af[im], bfr[in], acc[im][in], 0, 0, 0);
    }
  }

#pragma unroll
  for (int im = 0; im < 4; im++) {
#pragma unroll
    for (int in = 0; in < 4; in++) {
      const int col = n0 + wave_n * 64 + in * 16 + (lane & 15);
#pragma unroll
      for (int r = 0; r < 4; r++) {
        const int row = m0 + wave_m * 64 + im * 16 + (lane >> 4) * 4 + r;
        float val = acc[im][in][r] + bias[col];
        if (col < DIM) {
          out0[(size_t)row * DIM + col] = f2bf(Bvec[col] * val);
        } else {
          const int d = col - DIM;
          const float s = 1.f / (1.f + __expf(-val));
          out1[(size_t)row * DIM + d] = f2bf(Avec[d] * s);
        }
      }
    }
  }
}

// ---------------- fused out_proj + residual + layernorm ----------------
// Tile 64 rows x 512 cols (FULL N): each block owns complete output rows,
// so LN runs in the epilogue on f32 accumulators.
// Round-5 fixes vs round-4 (which showed FETCH 238 / WRITE 238 MB vs the
// 205/134 structural expectation):
//  (a) phase 1 overwrites acc with y = x + acc + bias -> phase 2 never
//      re-reads x (removes the second x pass);
//  (b) stores go through an LDS staging buffer (reusing the dead As/Bs
//      region, row stride 516 floats -> only free 2-way bank aliasing) and
//      are issued as float4 per lane, fully covering 128B lines -> kills
//      the partial-line write-amplification (scalar scatter stores covered
//      only 64B halves of lines, causing L2 RMW traffic).
// 512 threads = 8 waves, each wave one 64-col slice (wid = wave_n).
__global__ __launch_bounds__(512, 4) void gemm_ln(
    const ushort_t* __restrict__ Ag,   // h bf16 [M_TOT][DIM]
    const ushort_t* __restrict__ Bg,   // W_out bf16 [DIM][DIM]
    const float* __restrict__ bias,    // b_out
    const float* __restrict__ x,       // residual f32 [M_TOT][DIM]
    const float* __restrict__ gamma, const float* __restrict__ beta,
    float* __restrict__ out) {
  __shared__ __align__(16) char smem[73728];  // As 8KB + Bs 64KB; ebuf 64.5KB
  __shared__ float red[64][8][2];             // 4 KB
  __shared__ float stat[64][2];               // 0.5 KB
  ushort_t* As = (ushort_t*)smem;             // [64*64]
  ushort_t* Bs = (ushort_t*)(smem + 8192);    // [512*64]
  float* ebuf = (float*)smem;                 // [32][516] after K-loop

  const int tid = threadIdx.x;
  const int lane = tid & 63;
  const int wid = tid >> 6;     // wave_n 0..7 -> 64-col slice
  const int m0 = blockIdx.x * 64;

  floatx4 acc[4][4] = {};
  const int sr = tid >> 3;      // 0..63
  const int sc = tid & 7;

  for (int k0 = 0; k0 < K_DIM; k0 += 64) {
    __syncthreads();
    {  // A: 64 rows x 8 chunks = 512 chunks, 1 load/thread
      const int cg = sc ^ (sr & 7);
      async16(Ag + (size_t)(m0 + sr) * K_DIM + k0 + cg * 8,
              (char*)As + tid * 16);
    }
#pragma unroll
    for (int i = 0; i < 8; i++) {  // B: 512 rows, 8 loads/thread
      const int r = i * 64 + sr;
      const int cg = sc ^ (r & 7);
      async16(Bg + (size_t)r * K_DIM + k0 + cg * 8,
              (char*)Bs + i * 8192 + tid * 16);
    }
    __syncthreads();  // implies vmcnt(0): staged tile landed
#pragma unroll
    for (int kk = 0; kk < 2; kk++) {
      const int jc = kk * 4 + (lane >> 4);
      short8 af[4], bfr[4];
#pragma unroll
      for (int im = 0; im < 4; im++) {
        const int row = im * 16 + (lane & 15);
        af[im] = *(const short8*)((const char*)As + row * 128 +
                                  ((jc ^ (row & 7)) * 16));
      }
#pragma unroll
      for (int in = 0; in < 4; in++) {
        const int row = wid * 64 + in * 16 + (lane & 15);
        bfr[in] = *(const short8*)((const char*)Bs + row * 128 +
                                   ((jc ^ (row & 7)) * 16));
      }
#pragma unroll
      for (int im = 0; im < 4; im++)
#pragma unroll
        for (int in = 0; in < 4; in++)
          acc[im][in] = __builtin_amdgcn_mfma_f32_16x16x32_bf16(
              af[im], bfr[in], acc[im][in], 0, 0, 0);
    }
  }

  // ---- epilogue ----
  // thread frags: rows im*16+(lane>>4)*4+r (16), cols wid*64+in*16+(lane&15)
  float bcol[4];
#pragma unroll
  for (int in = 0; in < 4; in++)
    bcol[in] = bias[wid * 64 + in * 16 + (lane & 15)];

  // phase 1: y = x + acc + bias (stored back into acc); per-row partial sums
#pragma unroll
  for (int im = 0; im < 4; im++) {
#pragma unroll
    for (int r = 0; r < 4; r++) {
      const int rowl = im * 16 + (lane >> 4) * 4 + r;
      const size_t rowg = (size_t)(m0 + rowl);
      float s = 0.f, ss = 0.f;
#pragma unroll
      for (int in = 0; in < 4; in++) {
        const int col = wid * 64 + in * 16 + (lane & 15);
        const float y = x[rowg * DIM + col] + acc[im][in][r] + bcol[in];
        acc[im][in][r] = y;
        s += y; ss += y * y;
      }
#pragma unroll
      for (int m = 8; m >= 1; m >>= 1) {  // reduce the 16-lane col group
        s += __shfl_xor(s, m, 64);
        ss += __shfl_xor(ss, m, 64);
      }
      if ((lane & 15) == 0) {
        red[rowl][wid][0] = s;
        red[rowl][wid][1] = ss;
      }
    }
  }
  __syncthreads();   // also: all LDS reads of As/Bs retired -> ebuf reusable
  if (tid < 64) {
    float s = 0.f, ss = 0.f;
#pragma unroll
    for (int w = 0; w < 8; w++) { s += red[tid][w][0]; ss += red[tid][w][1]; }
    const float mean = s * (1.f / DIM);
    const float var = ss * (1.f / DIM) - mean * mean;
    stat[tid][0] = mean;
    stat[tid][1] = rsqrtf(var + 1e-5f);
  }
  __syncthreads();

  // phase 2: normalize from acc (no x re-read); stage into LDS; store
  // float4-coalesced. Two 32-row halves (ebuf = 32 x 516 f32).
#pragma unroll
  for (int h2 = 0; h2 < 2; h2++) {
#pragma unroll
    for (int imh = 0; imh < 2; imh++) {
      const int im = h2 * 2 + imh;
#pragma unroll
      for (int r = 0; r < 4; r++) {
        const int rowl = im * 16 + (lane >> 4) * 4 + r;
        const int rloc = rowl - h2 * 32;
        const float mean = stat[rowl][0], rstd = stat[rowl][1];
#pragma unroll
        for (int in = 0; in < 4; in++) {
          const int col = wid * 64 + in * 16 + (lane & 15);
          ebuf[rloc * 516 + col] =
              (acc[im][in][r] - mean) * rstd * gamma[col] + beta[col];
        }
      }
    }
    __syncthreads();
#pragma unroll
    for (int j = 0; j < 8; j++) {  // 4096 float4s, consecutive tid = coalesced
      const int f = j * 512 + tid;
      const int rloc = f >> 7;
      const int coli = (f & 127) * 4;
      const floatx4 v = *(const floatx4*)(ebuf + rloc * 516 + coli);
      *(floatx4*)(out + (size_t)(m0 + h2 * 32 + rloc) * DIM + coli) = v;
    }
    __syncthreads();  // ebuf free for next half
  }
}

// ---------------- chunked scan (round-0 proven versions) ----------------
// h_t = a_t * h_{t-1} + bz_t, independent per (b,d) pair, t in [0,2048).

// Pass 1: per chunk, local scan from h=0; emit prod(a) and local h_end.
__global__ __launch_bounds__(256) void scan_pass1(
    const ushort_t* __restrict__ a_arr, const ushort_t* __restrict__ bz_arr,
    float* __restrict__ pout, float* __restrict__ hout) {
  const int tid = blockIdx.x * 256 + threadIdx.x;  // 64*4096 threads
  const int c = tid >> 12;
  const int q = tid & 4095;
  size_t base = (size_t)(c * CLEN) * BD + q * 4;
  float h0 = 0.f, h1 = 0.f, h2 = 0.f, h3 = 0.f;
  float p0 = 1.f, p1 = 1.f, p2 = 1.f, p3 = 1.f;
#pragma unroll 8
  for (int t = 0; t < CLEN; t++) {
    ushort4v av = *(const ushort4v*)(a_arr + base + (size_t)t * BD);
    ushort4v bv = *(const ushort4v*)(bz_arr + base + (size_t)t * BD);
    float a0 = bf2f(av.x), a1 = bf2f(av.y), a2 = bf2f(av.z), a3 = bf2f(av.w);
    h0 = a0 * h0 + bf2f(bv.x); p0 *= a0;
    h1 = a1 * h1 + bf2f(bv.y); p1 *= a1;
    h2 = a2 * h2 + bf2f(bv.z); p2 *= a2;
    h3 = a3 * h3 + bf2f(bv.w); p3 *= a3;
  }
  const size_t ci = (size_t)c * BD + q * 4;
  *(floatx4*)(pout + ci) = (floatx4){p0, p1, p2, p3};
  *(floatx4*)(hout + ci) = (floatx4){h0, h1, h2, h3};
}

// Pass 2: sequentially combine chunk carries; carry[c] = h entering chunk c.
__global__ __launch_bounds__(256) void scan_pass2(
    const float* __restrict__ p, const float* __restrict__ hend,
    float* __restrict__ carry) {
  const int q = blockIdx.x * 256 + threadIdx.x;  // 4096 threads
  float h0 = 0.f, h1 = 0.f, h2 = 0.f, h3 = 0.f;
  for (int c = 0; c < NCHUNK; c++) {
    const size_t ci = (size_t)c * BD + q * 4;
    floatx4 pv = *(const floatx4*)(p + ci);
    floatx4 hv = *(const floatx4*)(hend + ci);
    *(floatx4*)(carry + ci) = (floatx4){h0, h1, h2, h3};
    h0 = hv.x + pv.x * h0;
    h1 = hv.y + pv.y * h1;
    h2 = hv.z + pv.z * h2;
    h3 = hv.w + pv.w * h3;
  }
}

// Pass 3: re-scan each chunk with its carry-in, write h (bf16).
__global__ __launch_bounds__(256) void scan_pass3(
    const ushort_t* __restrict__ a_arr, const ushort_t* __restrict__ bz_arr,
    const float* __restrict__ carry, ushort_t* __restrict__ h_arr) {
  const int tid = blockIdx.x * 256 + threadIdx.x;
  const int c = tid >> 12;
  const int q = tid & 4095;
  size_t base = (size_t)(c * CLEN) * BD + q * 4;
  const size_t ci = (size_t)c * BD + q * 4;
  floatx4 cv = *(const floatx4*)(carry + ci);
  float h0 = cv.x, h1 = cv.y, h2 = cv.z, h3 = cv.w;
#pragma unroll 8
  for (int t = 0; t < CLEN; t++) {
    ushort4v av = *(const ushort4v*)(a_arr + base + (size_t)t * BD);
    ushort4v bv = *(const ushort4v*)(bz_arr + base + (size_t)t * BD);
    h0 = bf2f(av.x) * h0 + bf2f(bv.x);
    h1 = bf2f(av.y) * h1 + bf2f(bv.y);
    h2 = bf2f(av.z) * h2 + bf2f(bv.z);
    h3 = bf2f(av.w) * h3 + bf2f(bv.w);
    ushort4v o;
    o.x = f2bf(h0); o.y = f2bf(h1); o.z = f2bf(h2); o.w = f2bf(h3);
    *(ushort4v*)(h_arr + base + (size_t)t * BD) = o;
  }
}

// ---------------- launch ----------------
extern "C" void kernel_launch(void* const* d_in, const int* in_sizes, int n_in,
                              void* d_out, int out_size, void* d_ws,
                              size_t ws_size, hipStream_t stream) {
  const float* x = (const float*)d_in[0];
  const float* W_in = (const float*)d_in[1];
  const float* b_in = (const float*)d_in[2];
  const float* W_out = (const float*)d_in[3];
  const float* b_out = (const float*)d_in[4];
  const float* Avec = (const float*)d_in[5];
  const float* Bvec = (const float*)d_in[6];
  const float* gamma = (const float*)d_in[7];
  const float* beta = (const float*)d_in[8];
  float* out = (float*)d_out;

  char* ws = (char*)d_ws;
  const size_t SZ64 = (size_t)M_TOT * DIM * 2;  // 64 MiB
  ushort_t* xb = (ushort_t*)ws;                  // x bf16; later reused as h
  ushort_t* gA = (ushort_t*)(ws + SZ64);         // gate*A
  ushort_t* bz = (ushort_t*)(ws + 2 * SZ64);     // B*z
  ushort_t* wib = (ushort_t*)(ws + 3 * SZ64);
  ushort_t* wob = (ushort_t*)(ws + 3 * SZ64 + (size_t)N1 * K_DIM * 2);
  char* p0 = ws + 3 * SZ64 + (size_t)N1 * K_DIM * 2 + (size_t)DIM * K_DIM * 2;
  float* pc = (float*)p0;                                   // 4 MiB
  float* hc = (float*)(p0 + (size_t)NCHUNK * BD * 4);       // 4 MiB
  float* cc = (float*)(p0 + 2 * (size_t)NCHUNK * BD * 4);   // 4 MiB

  // converts
  cvt_f32_bf16<<<(M_TOT * DIM / 4 + 255) / 256, 256, 0, stream>>>(
      x, xb, M_TOT * DIM / 4);
  cvt_f32_bf16<<<(N1 * K_DIM / 4 + 255) / 256, 256, 0, stream>>>(
      W_in, wib, N1 * K_DIM / 4);
  cvt_f32_bf16<<<(DIM * K_DIM / 4 + 255) / 256, 256, 0, stream>>>(
      W_out, wob, DIM * K_DIM / 4);

  // in_proj + gate epilogue (128x128 tiles, 512 m-tiles x 8 n-tiles)
  gemm_in<<<MT_TILES * 8, 256, 0, stream>>>(
      xb, wib, b_in, Avec, Bvec, bz, gA);

  // chunked scan
  scan_pass1<<<NCHUNK * (BD / 4) / 256, 256, 0, stream>>>(gA, bz, pc, hc);
  scan_pass2<<<(BD / 4) / 256, 256, 0, stream>>>(pc, hc, cc);
  scan_pass3<<<NCHUNK * (BD / 4) / 256, 256, 0, stream>>>(gA, bz, cc, xb);

  // fused out_proj + residual + layernorm (h = xb region)
  gemm_ln<<<M_TOT / 64, 512, 0, stream>>>(
      xb, wob, b_out, x, gamma, beta, out);
}